// Round 3
// baseline (190.058 us; speedup 1.0000x reference)
//
#include <hip/hip_runtime.h>
#include <cstdint>

// B=16384 rows, K=2048 centers, D=128, T=1.0
// Outputs (flat, f32): out[B*D], center[K*D], label[B]
#define NB 16384
#define NK 2048
#define ND 128

// ---------------------------------------------------------------------------
// Fused prep: x2 + partial-init (blocks 0..4095), transpose (4096..5119),
// center passthrough copy (5120..5375), c2 (5376..5383).
// Arithmetic IDENTICAL to the round-1/2 passing kernels.
// ---------------------------------------------------------------------------
__global__ __launch_bounds__(256)
void prep(const float* __restrict__ x,
          const float* __restrict__ c,
          float* __restrict__ cT,
          float* __restrict__ c2,
          float* __restrict__ x2,
          float* __restrict__ out_center,
          unsigned long long* __restrict__ partial) {
    const int bid = blockIdx.x;
    const int tid = threadIdx.x;
    if (bid < 4096) {
        // x2: one wave per row, same butterfly order as round 1
        const int row  = bid * 4 + (tid >> 6);
        const int lane = tid & 63;
        float2 v = ((const float2*)(x + (long)row * ND))[lane];
        float s = v.x * v.x + v.y * v.y;
#pragma unroll
        for (int off = 32; off; off >>= 1) s += __shfl_xor(s, off, 64);
        if (lane == 0) {
            x2[row] = s;
            partial[row] = ~0ULL;            // init for atomicMin
        }
    } else if (bid < 5120) {
        // transpose center [K][D] -> cT [D][K]
        int t = (bid - 4096) * 256 + tid;    // 0 .. K*D-1
        int d = t >> 11;
        int k = t & (NK - 1);
        cT[t] = c[k * ND + d];
    } else if (bid < 5376) {
        // center passthrough, float4
        int i = (bid - 5120) * 256 + tid;    // 0 .. K*D/4-1
        ((float4*)out_center)[i] = ((const float4*)c)[i];
    } else {
        // c2[k], same expression/order as round 1
        int k = (bid - 5376) * 256 + tid;    // 0 .. K-1
        const float4* row = (const float4*)(c + (long)k * ND);
        float s = 0.f;
#pragma unroll 8
        for (int i = 0; i < ND / 4; ++i) {
            float4 v = row[i];
            s += v.x * v.x + v.y * v.y + v.z * v.z + v.w * v.w;
        }
        c2[k] = s;
    }
}

// ---------------------------------------------------------------------------
// Main: 2048 blocks x 256 threads (4 waves). Block = one k-quarter for a
// 32-row group; wave handles 8 rows; lane handles 4 consecutive k per 256-k
// chunk (2 chunks per quarter). 256-thread blocks pack 8 blocks/CU -> full
// residency (512-thread blocks capped at ~1.4 blocks/CU, R2 post-mortem).
// Per-row result combined across quarters via atomicMin on packed u64 key.
// ---------------------------------------------------------------------------
__global__ __launch_bounds__(256)
void kmeans_main(const float* __restrict__ x,
                 const float* __restrict__ cT,
                 const float* __restrict__ c2,
                 const float* __restrict__ x2,
                 unsigned long long* __restrict__ partial) {
    const int lane = threadIdx.x & 63;
    const int wave = __builtin_amdgcn_readfirstlane(threadIdx.x >> 6); // 0..3
    const int qa = blockIdx.x & 3;                  // k-quarter
    const int rg = blockIdx.x >> 2;                 // row-group of 32 rows
    const long row_base = (long)rg * 32 + wave * 8;
    const float* __restrict__ xr = x + row_base * ND;  // wave-uniform base

    float x2v[8];
#pragma unroll
    for (int r = 0; r < 8; ++r) x2v[r] = x2[row_base + r];  // uniform -> s_load

    float bestS[8];
    int   bestK[8];
#pragma unroll
    for (int r = 0; r < 8; ++r) { bestS[r] = __builtin_inff(); bestK[r] = 0; }

    for (int chunk = 0; chunk < 2; ++chunk) {
        const int kk = qa * 512 + chunk * 256 + lane * 4;  // lane's 4 k's
        float acc[8][4];
#pragma unroll
        for (int r = 0; r < 8; ++r)
#pragma unroll
            for (int j = 0; j < 4; ++j) acc[r][j] = 0.f;

        const float4* cptr = (const float4*)(cT + kk);     // row stride 512 f4
#pragma unroll 4
        for (int d = 0; d < ND; ++d) {
            float4 c4 = cptr[d * (NK / 4)];
#pragma unroll
            for (int r = 0; r < 8; ++r) {
                float xv = xr[r * ND + d];                 // uniform -> s_load
                acc[r][0] = fmaf(xv, c4.x, acc[r][0]);
                acc[r][1] = fmaf(xv, c4.y, acc[r][1]);
                acc[r][2] = fmaf(xv, c4.z, acc[r][2]);
                acc[r][3] = fmaf(xv, c4.w, acc[r][3]);
            }
        }

        float4 c2v = *(const float4*)(c2 + kk);
        float c2a[4] = {c2v.x, c2v.y, c2v.z, c2v.w};
#pragma unroll
        for (int r = 0; r < 8; ++r) {
#pragma unroll
            for (int j = 0; j < 4; ++j) {
                // Same fp32 chain as the exact-passing round-1 kernel.
                float t = x2v[r] + c2a[j];
                float f = fmaf(-2.0f, acc[r][j], t);
                f = fmaxf(f, 0.0f);
                float s = __builtin_sqrtf(f);
                // lane visits k strictly ascending -> strict < keeps lowest k
                if (s < bestS[r]) { bestS[r] = s; bestK[r] = kk + j; }
            }
        }
    }

    // Pack key once, wave-butterfly u64 min, one atomic per (row, quarter).
#pragma unroll
    for (int r = 0; r < 8; ++r) {
        unsigned long long b =
            ((unsigned long long)__float_as_uint(bestS[r]) << 32) |
            (unsigned)bestK[r];
#pragma unroll
        for (int off = 32; off; off >>= 1) {
            unsigned long long o = __shfl_xor(b, off, 64);
            if (o < b) b = o;
        }
        if (lane == 0) atomicMin(&partial[row_base + r], b);
    }
}

// ---------------------------------------------------------------------------
// Merge: one wave per row — read final key, gather center row, write label.
// ---------------------------------------------------------------------------
__global__ __launch_bounds__(256)
void merge(const unsigned long long* __restrict__ partial,
           const float* __restrict__ center,
           float* __restrict__ out,
           float* __restrict__ label_out) {
    const long row  = (long)blockIdx.x * 4 + (threadIdx.x >> 6);
    const int  lane = threadIdx.x & 63;
    unsigned long long b = partial[row];                 // uniform broadcast
    int bk = (int)(b & 0xffffffffULL);
    float2 cv = ((const float2*)(center + (long)bk * ND))[lane];
    ((float2*)(out + row * ND))[lane] = cv;
    if (lane == 0) label_out[row] = (float)bk;
}

// ---------------------------------------------------------------------------
extern "C" void kernel_launch(void* const* d_in, const int* in_sizes, int n_in,
                              void* d_out, int out_size, void* d_ws, size_t ws_size,
                              hipStream_t stream) {
    const float* x      = (const float*)d_in[0];   // [B][D]
    const float* center = (const float*)d_in[1];   // [K][D]
    float* out = (float*)d_out;

    float* out_x      = out;                        // [B*D]
    float* out_center = out + (long)NB * ND;        // [K*D]
    float* out_label  = out_center + (long)NK * ND; // [B]

    // Workspace: cT[K*D], c2[K], x2[B], partial[B] (u64)  (~1.25 MB)
    float* cT = (float*)d_ws;
    float* c2 = cT + (long)NK * ND;
    float* x2 = c2 + NK;
    unsigned long long* partial = (unsigned long long*)(x2 + NB);

    prep<<<5384, 256, 0, stream>>>(x, center, cT, c2, x2, out_center, partial);
    kmeans_main<<<2048, 256, 0, stream>>>(x, cT, c2, x2, partial);
    merge<<<NB / 4, 256, 0, stream>>>(partial, center, out_x, out_label);
}

// Round 4
// 133.171 us; speedup vs baseline: 1.4272x; 1.4272x over previous
//
#include <hip/hip_runtime.h>
#include <cstdint>

// B=16384 rows, K=2048 centers, D=128, T=1.0
// Outputs (flat, f32): out[B*D], center[K*D], label[B]
#define NB 16384
#define NK 2048
#define ND 128
#define MARGIN 0.10f
#define CAP 4096

typedef __attribute__((ext_vector_type(8))) short bf16x8;
typedef __attribute__((ext_vector_type(4))) float f32x4;
typedef unsigned long long u64;

__device__ __forceinline__ unsigned short f2bf(float f) {
    unsigned u = __float_as_uint(f);
    u += 0x7fffu + ((u >> 16) & 1u);          // round-to-nearest-even
    return (unsigned short)(u >> 16);
}

// ---------------------------------------------------------------------------
// Fused prep:
//  [0,4096)    x2 (one wave/row, chain identical to R1) + init gmin/partial
//  [4096,5120) xbf: x -> bf16 in MFMA A-frag layout
//  [5120,5248) cbf: center -> bf16 in MFMA B-frag layout
//  [5248,5256) c2 (chain identical to R1)
//  [5256,5512) center passthrough copy (float4)
// Frag layout (16x16x32 bf16): elem = lane&15, k = (lane>>4)*8 + j; flat
// index = ((tile*4 + step)*64 + lane)*8 shorts, tile = elem/16 along M or N.
// ---------------------------------------------------------------------------
__global__ __launch_bounds__(256)
void prep(const float* __restrict__ x,
          const float* __restrict__ c,
          unsigned short* __restrict__ xbf,
          unsigned short* __restrict__ cbf,
          float* __restrict__ c2,
          float* __restrict__ x2,
          unsigned int* __restrict__ gmin,
          u64* __restrict__ partial,
          float* __restrict__ out_center) {
    const int bid = blockIdx.x;
    const int tid = threadIdx.x;
    if (bid < 4096) {
        const int row  = bid * 4 + (tid >> 6);
        const int lane = tid & 63;
        float2 v = ((const float2*)(x + (long)row * ND))[lane];
        float s = v.x * v.x + v.y * v.y;
#pragma unroll
        for (int off = 32; off; off >>= 1) s += __shfl_xor(s, off, 64);
        if (lane == 0) {
            x2[row] = s;
            gmin[row] = 0x7f800000u;          // +inf
            partial[row] = ~0ULL;
        }
    } else if (bid < 5120) {
        int t = (bid - 4096) * 256 + tid;     // 0..262143
        int lane = t & 63, s = (t >> 6) & 3, rt = t >> 8;
        int row = rt * 16 + (lane & 15);
        int d0  = s * 32 + (lane >> 4) * 8;
        const float* src = x + (long)row * ND + d0;
        unsigned short h[8];
#pragma unroll
        for (int j = 0; j < 8; ++j) h[j] = f2bf(src[j]);
        int4 pk;
        pk.x = h[0] | (h[1] << 16); pk.y = h[2] | (h[3] << 16);
        pk.z = h[4] | (h[5] << 16); pk.w = h[6] | (h[7] << 16);
        ((int4*)xbf)[t] = pk;
    } else if (bid < 5248) {
        int t = (bid - 5120) * 256 + tid;     // 0..32767
        int lane = t & 63, s = (t >> 6) & 3, kt = t >> 8;
        int kc = kt * 16 + (lane & 15);
        int d0 = s * 32 + (lane >> 4) * 8;
        const float* src = c + (long)kc * ND + d0;
        unsigned short h[8];
#pragma unroll
        for (int j = 0; j < 8; ++j) h[j] = f2bf(src[j]);
        int4 pk;
        pk.x = h[0] | (h[1] << 16); pk.y = h[2] | (h[3] << 16);
        pk.z = h[4] | (h[5] << 16); pk.w = h[6] | (h[7] << 16);
        ((int4*)cbf)[t] = pk;
    } else if (bid < 5256) {
        int k = (bid - 5248) * 256 + tid;
        const float4* row = (const float4*)(c + (long)k * ND);
        float s = 0.f;
#pragma unroll 8
        for (int i = 0; i < ND / 4; ++i) {
            float4 v = row[i];
            s += v.x * v.x + v.y * v.y + v.z * v.z + v.w * v.w;
        }
        c2[k] = s;
    } else {
        int i = (bid - 5256) * 256 + tid;     // 0..K*D/4-1
        ((float4*)out_center)[i] = ((const float4*)c)[i];
    }
}

// ---------------------------------------------------------------------------
// Shared MFMA tile: wave = 32 rows x 64 k, K=128 in 4 steps. Block = 4 waves
// (same 32 rows, 256-k span). Grid 4096 = 512 row-groups x 8 k-blocks.
// C layout: col = lane&15 (k within tile), row = (lane>>4)*4 + reg.
// ---------------------------------------------------------------------------
__device__ __forceinline__ void mfma_d2_tile(
        const unsigned short* __restrict__ xbf,
        const unsigned short* __restrict__ cbf,
        const float* __restrict__ c2,
        const float* __restrict__ x2,
        int rg, int colbase, int lane,
        f32x4 acc[2][4], float c2v[4], float x2v[2][4]) {
    const bf16x8* XF = (const bf16x8*)xbf;
    const bf16x8* CF = (const bf16x8*)cbf;
#pragma unroll
    for (int rt = 0; rt < 2; ++rt)
#pragma unroll
        for (int ct = 0; ct < 4; ++ct) acc[rt][ct] = (f32x4){0.f, 0.f, 0.f, 0.f};
#pragma unroll
    for (int s = 0; s < 4; ++s) {
        bf16x8 a0 = XF[((rg * 2 + 0) * 4 + s) * 64 + lane];
        bf16x8 a1 = XF[((rg * 2 + 1) * 4 + s) * 64 + lane];
#pragma unroll
        for (int ct = 0; ct < 4; ++ct) {
            bf16x8 b = CF[(((colbase >> 4) + ct) * 4 + s) * 64 + lane];
            acc[0][ct] = __builtin_amdgcn_mfma_f32_16x16x32_bf16(a0, b, acc[0][ct], 0, 0, 0);
            acc[1][ct] = __builtin_amdgcn_mfma_f32_16x16x32_bf16(a1, b, acc[1][ct], 0, 0, 0);
        }
    }
#pragma unroll
    for (int ct = 0; ct < 4; ++ct) c2v[ct] = c2[colbase + ct * 16 + (lane & 15)];
#pragma unroll
    for (int rt = 0; rt < 2; ++rt)
#pragma unroll
        for (int reg = 0; reg < 4; ++reg)
            x2v[rt][reg] = x2[rg * 32 + rt * 16 + (lane >> 4) * 4 + reg];
}

__global__ __launch_bounds__(256)
void pass1(const unsigned short* __restrict__ xbf,
           const unsigned short* __restrict__ cbf,
           const float* __restrict__ c2,
           const float* __restrict__ x2,
           unsigned int* __restrict__ gmin) {
    const int lane = threadIdx.x & 63;
    const int wave = __builtin_amdgcn_readfirstlane(threadIdx.x >> 6);
    const int rg = blockIdx.x >> 3;
    const int colbase = (blockIdx.x & 7) * 256 + wave * 64;

    f32x4 acc[2][4]; float c2v[4], x2v[2][4];
    mfma_d2_tile(xbf, cbf, c2, x2, rg, colbase, lane, acc, c2v, x2v);

    float rmin[2][4];
#pragma unroll
    for (int rt = 0; rt < 2; ++rt)
#pragma unroll
        for (int reg = 0; reg < 4; ++reg) rmin[rt][reg] = __builtin_inff();
#pragma unroll
    for (int rt = 0; rt < 2; ++rt)
#pragma unroll
        for (int ct = 0; ct < 4; ++ct)
#pragma unroll
            for (int reg = 0; reg < 4; ++reg) {
                float d2 = fmaf(-2.f, acc[rt][ct][reg], x2v[rt][reg] + c2v[ct]);
                rmin[rt][reg] = fminf(rmin[rt][reg], d2);
            }
#pragma unroll
    for (int off = 1; off < 16; off <<= 1)
#pragma unroll
        for (int rt = 0; rt < 2; ++rt)
#pragma unroll
            for (int reg = 0; reg < 4; ++reg)
                rmin[rt][reg] = fminf(rmin[rt][reg], __shfl_xor(rmin[rt][reg], off, 64));
    if ((lane & 15) == 0) {
#pragma unroll
        for (int rt = 0; rt < 2; ++rt)
#pragma unroll
            for (int reg = 0; reg < 4; ++reg) {
                int row = rg * 32 + rt * 16 + (lane >> 4) * 4 + reg;
                atomicMin(&gmin[row], __float_as_uint(rmin[rt][reg]));
            }
    }
}

__global__ __launch_bounds__(256)
void pass2(const unsigned short* __restrict__ xbf,
           const unsigned short* __restrict__ cbf,
           const float* __restrict__ c2,
           const float* __restrict__ x2,
           const unsigned int* __restrict__ gmin,
           const float* __restrict__ x,
           const float* __restrict__ center,
           u64* __restrict__ partial) {
    __shared__ unsigned int cnt;
    __shared__ unsigned int buf[CAP];
    if (threadIdx.x == 0) cnt = 0;
    __syncthreads();

    const int lane = threadIdx.x & 63;
    const int wave = __builtin_amdgcn_readfirstlane(threadIdx.x >> 6);
    const int rg = blockIdx.x >> 3;
    const int colbase = (blockIdx.x & 7) * 256 + wave * 64;

    f32x4 acc[2][4]; float c2v[4], x2v[2][4];
    mfma_d2_tile(xbf, cbf, c2, x2, rg, colbase, lane, acc, c2v, x2v);

    float thr[2][4];
#pragma unroll
    for (int rt = 0; rt < 2; ++rt)
#pragma unroll
        for (int reg = 0; reg < 4; ++reg) {
            int row = rg * 32 + rt * 16 + (lane >> 4) * 4 + reg;
            thr[rt][reg] = __uint_as_float(gmin[row]) + MARGIN;
        }
#pragma unroll
    for (int rt = 0; rt < 2; ++rt)
#pragma unroll
        for (int ct = 0; ct < 4; ++ct)
#pragma unroll
            for (int reg = 0; reg < 4; ++reg) {
                float d2 = fmaf(-2.f, acc[rt][ct][reg], x2v[rt][reg] + c2v[ct]);
                if (d2 <= thr[rt][reg]) {
                    int row = rg * 32 + rt * 16 + (lane >> 4) * 4 + reg;
                    int col = colbase + ct * 16 + (lane & 15);
                    unsigned idx = atomicAdd(&cnt, 1u);
                    if (idx < CAP) buf[idx] = ((unsigned)row << 11) | (unsigned)col;
                }
            }
    __syncthreads();
    unsigned n = cnt; if (n > CAP) n = CAP;
    // Exact refine: fp32 chain IDENTICAL to the R1-passing kernel
    // (serial fmaf dot d=0..127, t=x2+c2, fmaf(-2,dot,t), max, sqrt),
    // packed key keeps tie -> lowest k.
    for (unsigned i = threadIdx.x; i < n; i += 256) {
        unsigned pc = buf[i];
        int row = pc >> 11, col = pc & (NK - 1);
        const float* xr = x + (long)row * ND;
        const float* cr = center + (long)col * ND;
        float dot = 0.f;
#pragma unroll 8
        for (int d = 0; d < ND; ++d) dot = fmaf(xr[d], cr[d], dot);
        float t = x2[row] + c2[col];
        float f = fmaxf(fmaf(-2.0f, dot, t), 0.0f);
        float s = __builtin_sqrtf(f);
        u64 key = ((u64)__float_as_uint(s) << 32) | (unsigned)col;
        atomicMin(&partial[row], key);
    }
}

// ---------------------------------------------------------------------------
// Merge: one wave per row — read final key, gather center row, write label.
// ---------------------------------------------------------------------------
__global__ __launch_bounds__(256)
void merge(const u64* __restrict__ partial,
           const float* __restrict__ center,
           float* __restrict__ out,
           float* __restrict__ label_out) {
    const long row  = (long)blockIdx.x * 4 + (threadIdx.x >> 6);
    const int  lane = threadIdx.x & 63;
    u64 b = partial[row];
    int bk = (int)(b & 0xffffffffULL);
    float2 cv = ((const float2*)(center + (long)bk * ND))[lane];
    ((float2*)(out + row * ND))[lane] = cv;
    if (lane == 0) label_out[row] = (float)bk;
}

// ---------------------------------------------------------------------------
extern "C" void kernel_launch(void* const* d_in, const int* in_sizes, int n_in,
                              void* d_out, int out_size, void* d_ws, size_t ws_size,
                              hipStream_t stream) {
    const float* x      = (const float*)d_in[0];   // [B][D]
    const float* center = (const float*)d_in[1];   // [K][D]
    float* out = (float*)d_out;

    float* out_x      = out;                        // [B*D]
    float* out_center = out + (long)NB * ND;        // [K*D]
    float* out_label  = out_center + (long)NK * ND; // [B]

    // Workspace: xbf[B*D]u16 (4MB), cbf[K*D]u16 (0.5MB), partial[B]u64,
    // gmin[B]u32, c2[K]f32, x2[B]f32   (~4.8 MB total)
    unsigned short* xbf = (unsigned short*)d_ws;
    unsigned short* cbf = xbf + (size_t)NB * ND;
    u64*      partial = (u64*)(cbf + (size_t)NK * ND);
    unsigned* gmin    = (unsigned*)(partial + NB);
    float*    c2      = (float*)(gmin + NB);
    float*    x2      = c2 + NK;

    prep<<<5512, 256, 0, stream>>>(x, center, xbf, cbf, c2, x2, gmin, partial,
                                   out_center);
    pass1<<<4096, 256, 0, stream>>>(xbf, cbf, c2, x2, gmin);
    pass2<<<4096, 256, 0, stream>>>(xbf, cbf, c2, x2, gmin, x, center, partial);
    merge<<<NB / 4, 256, 0, stream>>>(partial, center, out_x, out_label);
}

// Round 5
// 120.475 us; speedup vs baseline: 1.5776x; 1.1054x over previous
//
#include <hip/hip_runtime.h>
#include <cstdint>

// B=16384 rows, K=2048 centers, D=128, T=1.0
// Outputs (flat, f32): out[B*D], center[K*D], label[B]
#define NB 16384
#define NK 2048
#define ND 128
#define MARGIN 0.10f
#define CAP 2048
#define XPITCH 132   // padded LDS x-row stride (floats): breaks bank aliasing

typedef __attribute__((ext_vector_type(8))) short bf16x8;
typedef __attribute__((ext_vector_type(4))) float f32x4;
typedef unsigned long long u64;

__device__ __forceinline__ unsigned short f2bf(float f) {
    unsigned u = __float_as_uint(f);
    u += 0x7fffu + ((u >> 16) & 1u);          // round-to-nearest-even
    return (unsigned short)(u >> 16);
}

// ---------------------------------------------------------------------------
// Prep (392 blocks):
//  [0,128)    cbf: center -> bf16 MFMA B-frag layout (identical to R4)
//  [128,136)  c2 (chain identical to R1)
//  [136,392)  center passthrough copy (float4)
// ---------------------------------------------------------------------------
__global__ __launch_bounds__(256)
void prep(const float* __restrict__ c,
          unsigned short* __restrict__ cbf,
          float* __restrict__ c2,
          float* __restrict__ out_center) {
    const int bid = blockIdx.x;
    const int tid = threadIdx.x;
    if (bid < 128) {
        int t = bid * 256 + tid;              // 0..32767
        int lane = t & 63, s = (t >> 6) & 3, kt = t >> 8;
        int kc = kt * 16 + (lane & 15);
        int d0 = s * 32 + (lane >> 4) * 8;
        const float* src = c + (long)kc * ND + d0;
        unsigned short h[8];
#pragma unroll
        for (int j = 0; j < 8; ++j) h[j] = f2bf(src[j]);
        int4 pk;
        pk.x = h[0] | (h[1] << 16); pk.y = h[2] | (h[3] << 16);
        pk.z = h[4] | (h[5] << 16); pk.w = h[6] | (h[7] << 16);
        ((int4*)cbf)[t] = pk;
    } else if (bid < 136) {
        int k = (bid - 128) * 256 + tid;      // 0..2047
        const float4* row = (const float4*)(c + (long)k * ND);
        float s = 0.f;
#pragma unroll 8
        for (int i = 0; i < ND / 4; ++i) {
            float4 v = row[i];
            s += v.x * v.x + v.y * v.y + v.z * v.z + v.w * v.w;
        }
        c2[k] = s;
    } else {
        int i = (bid - 136) * 256 + tid;      // 0..K*D/4-1
        ((float4*)out_center)[i] = ((const float4*)c)[i];
    }
}

// ---------------------------------------------------------------------------
// Main: 512 blocks x 256 threads. Block owns 32 rows x ALL 2048 k -> block
// min IS the global min (no cross-block combine). Wave w covers k in
// [w*512, w*512+512). Two MFMA sweeps (min, then filter) + exact fp32 refine
// with the R1-identical chain; direct out/label writes.
// ---------------------------------------------------------------------------
__global__ __launch_bounds__(256)
void kmeans_main(const float* __restrict__ x,
                 const float* __restrict__ center,
                 const unsigned short* __restrict__ cbf,
                 const float* __restrict__ c2,
                 float* __restrict__ out,
                 float* __restrict__ label_out) {
    __shared__ float xs[32 * XPITCH];         // 16.9 KB fp32 x rows
    __shared__ float x2s[32];
    __shared__ unsigned bmin[32];
    __shared__ u64 best[32];
    __shared__ unsigned buf[CAP];             // 8 KB candidate list
    __shared__ unsigned cnt;

    const int tid  = threadIdx.x;
    const int lane = tid & 63;
    const int wave = __builtin_amdgcn_readfirstlane(tid >> 6);  // 0..3
    const long rb  = (long)blockIdx.x * 32;

    // ---- stage x rows -> LDS (coalesced, 16 floats/thread) ----
    {
        int r = tid >> 3, q = tid & 7;
        const float4* src = (const float4*)(x + (rb + r) * ND + q * 16);
        float4 v0 = src[0], v1 = src[1], v2 = src[2], v3 = src[3];
        float* dst = xs + r * XPITCH + q * 16;
        ((float4*)dst)[0] = v0; ((float4*)dst)[1] = v1;
        ((float4*)dst)[2] = v2; ((float4*)dst)[3] = v3;
    }
    if (tid < 32) { bmin[tid] = 0x7f800000u; best[tid] = ~0ULL; }
    if (tid == 0) cnt = 0;
    __syncthreads();

    // ---- x2 per row: chain IDENTICAL to R1 (float2, 6-level butterfly) ----
    for (int i = 0; i < 8; ++i) {
        int r = wave * 8 + i;
        float2 v = *(const float2*)(xs + r * XPITCH + lane * 2);
        float s = v.x * v.x + v.y * v.y;
#pragma unroll
        for (int off = 32; off; off >>= 1) s += __shfl_xor(s, off, 64);
        if (lane == 0) x2s[r] = s;
    }
    __syncthreads();

    // ---- A-frags into registers (reused by both sweeps) ----
    bf16x8 af[2][4];
#pragma unroll
    for (int rt = 0; rt < 2; ++rt)
#pragma unroll
        for (int s = 0; s < 4; ++s) {
            const float* p = xs + (rt * 16 + (lane & 15)) * XPITCH
                               + s * 32 + (lane >> 4) * 8;
            float4 u0 = ((const float4*)p)[0];
            float4 u1 = ((const float4*)p)[1];
            bf16x8 a;
            a[0] = (short)f2bf(u0.x); a[1] = (short)f2bf(u0.y);
            a[2] = (short)f2bf(u0.z); a[3] = (short)f2bf(u0.w);
            a[4] = (short)f2bf(u1.x); a[5] = (short)f2bf(u1.y);
            a[6] = (short)f2bf(u1.z); a[7] = (short)f2bf(u1.w);
            af[rt][s] = a;
        }

    float x2p[2][4];
#pragma unroll
    for (int rt = 0; rt < 2; ++rt)
#pragma unroll
        for (int reg = 0; reg < 4; ++reg)
            x2p[rt][reg] = x2s[rt * 16 + (lane >> 4) * 4 + reg];

    const bf16x8* CF = (const bf16x8*)cbf;
    const int kbase = wave * 512;

    // ---- sweep 1: min over this wave's 512 k ----
    float rmin[2][4];
#pragma unroll
    for (int rt = 0; rt < 2; ++rt)
#pragma unroll
        for (int reg = 0; reg < 4; ++reg) rmin[rt][reg] = __builtin_inff();

#pragma unroll 2
    for (int ct = 0; ct < 32; ++ct) {
        const int kt = (kbase >> 4) + ct;     // 16-k tile index
        bf16x8 bf[4];
#pragma unroll
        for (int s = 0; s < 4; ++s) bf[s] = CF[(kt * 4 + s) * 64 + lane];
        f32x4 acc0 = {0.f,0.f,0.f,0.f}, acc1 = {0.f,0.f,0.f,0.f};
#pragma unroll
        for (int s = 0; s < 4; ++s) {
            acc0 = __builtin_amdgcn_mfma_f32_16x16x32_bf16(af[0][s], bf[s], acc0, 0,0,0);
            acc1 = __builtin_amdgcn_mfma_f32_16x16x32_bf16(af[1][s], bf[s], acc1, 0,0,0);
        }
        float c2v = c2[kt * 16 + (lane & 15)];
#pragma unroll
        for (int reg = 0; reg < 4; ++reg) {
            rmin[0][reg] = fminf(rmin[0][reg], fmaf(-2.f, acc0[reg], x2p[0][reg] + c2v));
            rmin[1][reg] = fminf(rmin[1][reg], fmaf(-2.f, acc1[reg], x2p[1][reg] + c2v));
        }
    }

    // cross-lane min over the 16 cols (lane&15 group), then block combine
#pragma unroll
    for (int rt = 0; rt < 2; ++rt)
#pragma unroll
        for (int reg = 0; reg < 4; ++reg) {
            float v = rmin[rt][reg];
#pragma unroll
            for (int off = 1; off < 16; off <<= 1)
                v = fminf(v, __shfl_xor(v, off, 64));
            if ((lane & 15) == 0)             // d2a >= 0 -> uint order == float order
                atomicMin(&bmin[rt * 16 + (lane >> 4) * 4 + reg], __float_as_uint(v));
        }
    __syncthreads();

    float thr[2][4];
#pragma unroll
    for (int rt = 0; rt < 2; ++rt)
#pragma unroll
        for (int reg = 0; reg < 4; ++reg)
            thr[rt][reg] = __uint_as_float(bmin[rt * 16 + (lane >> 4) * 4 + reg]) + MARGIN;

    // ---- sweep 2: recompute, filter candidates within MARGIN of block min ----
#pragma unroll 2
    for (int ct = 0; ct < 32; ++ct) {
        const int kt = (kbase >> 4) + ct;
        bf16x8 bf[4];
#pragma unroll
        for (int s = 0; s < 4; ++s) bf[s] = CF[(kt * 4 + s) * 64 + lane];
        f32x4 acc0 = {0.f,0.f,0.f,0.f}, acc1 = {0.f,0.f,0.f,0.f};
#pragma unroll
        for (int s = 0; s < 4; ++s) {
            acc0 = __builtin_amdgcn_mfma_f32_16x16x32_bf16(af[0][s], bf[s], acc0, 0,0,0);
            acc1 = __builtin_amdgcn_mfma_f32_16x16x32_bf16(af[1][s], bf[s], acc1, 0,0,0);
        }
        float c2v = c2[kt * 16 + (lane & 15)];
        const int col = kt * 16 + (lane & 15);
#pragma unroll
        for (int reg = 0; reg < 4; ++reg) {
            float d20 = fmaf(-2.f, acc0[reg], x2p[0][reg] + c2v);
            if (d20 <= thr[0][reg]) {
                unsigned rloc = (lane >> 4) * 4 + reg;          // rt=0
                unsigned idx = atomicAdd(&cnt, 1u);
                if (idx < CAP) buf[idx] = (rloc << 11) | (unsigned)col;
            }
            float d21 = fmaf(-2.f, acc1[reg], x2p[1][reg] + c2v);
            if (d21 <= thr[1][reg]) {
                unsigned rloc = 16 + (lane >> 4) * 4 + reg;     // rt=1
                unsigned idx = atomicAdd(&cnt, 1u);
                if (idx < CAP) buf[idx] = (rloc << 11) | (unsigned)col;
            }
        }
    }
    __syncthreads();

    // ---- exact refine: fp32 chain IDENTICAL to R1 (serial fmaf dot,
    //      t=x2+c2, fmaf(-2,dot,t), max, sqrt; u64 key -> lowest k on tie) ----
    unsigned n = cnt; if (n > CAP) n = CAP;
    for (unsigned i = tid; i < n; i += 256) {
        unsigned pc = buf[i];
        int rloc = pc >> 11, col = pc & (NK - 1);
        const float* xr = xs + rloc * XPITCH;
        const float* cr = center + (long)col * ND;
        float dot = 0.f;
#pragma unroll 8
        for (int d = 0; d < ND; ++d) dot = fmaf(xr[d], cr[d], dot);
        float t = x2s[rloc] + c2[col];
        float f = fmaxf(fmaf(-2.0f, dot, t), 0.0f);
        float s = __builtin_sqrtf(f);
        u64 key = ((u64)__float_as_uint(s) << 32) | (unsigned)col;
        atomicMin(&best[rloc], key);
    }
    __syncthreads();

    // ---- direct output: gather center[bk] per row + label ----
    for (int i = 0; i < 8; ++i) {
        int rloc = wave * 8 + i;
        int bk = (int)(best[rloc] & 0xffffffffULL);
        float2 cv = ((const float2*)(center + (long)bk * ND))[lane];
        ((float2*)(out + (rb + rloc) * ND))[lane] = cv;
        if (lane == 0) label_out[rb + rloc] = (float)bk;
    }
}

// ---------------------------------------------------------------------------
extern "C" void kernel_launch(void* const* d_in, const int* in_sizes, int n_in,
                              void* d_out, int out_size, void* d_ws, size_t ws_size,
                              hipStream_t stream) {
    const float* x      = (const float*)d_in[0];   // [B][D]
    const float* center = (const float*)d_in[1];   // [K][D]
    float* out = (float*)d_out;

    float* out_x      = out;                        // [B*D]
    float* out_center = out + (long)NB * ND;        // [K*D]
    float* out_label  = out_center + (long)NK * ND; // [B]

    // Workspace: cbf[K*D]u16 (0.5MB), c2[K]f32
    unsigned short* cbf = (unsigned short*)d_ws;
    float* c2 = (float*)(cbf + (size_t)NK * ND);

    prep<<<392, 256, 0, stream>>>(center, cbf, c2, out_center);
    kmeans_main<<<NB / 32, 256, 0, stream>>>(x, center, cbf, c2,
                                             out_x, out_label);
}